// Round 3
// baseline (163.143 us; speedup 1.0000x reference)
//
#include <hip/hip_runtime.h>
#include <hip/hip_bf16.h>
#include <type_traits>
#include <stdint.h>

// ---- problem constants ----
static constexpr int BB   = 4;
static constexpr int SS   = 1024;
static constexpr int HH   = 32;
static constexpr int HKV  = 8;
static constexpr int GG   = 4;      // H / HKV
static constexpr int DD   = 128;
static constexpr int PAGE = 128;    // paged-cache block size
static constexpr int NBLK = 64;     // cache blocks
static constexpr int QBLK = 128;    // q rows per q-tile (4 waves x 32)
static constexpr int KVB  = 64;     // kv rows per tile
static constexpr int NT   = SS / KVB;   // 16 kv tiles per (b,hkv)

static constexpr int KROW = 272;    // K_lds row stride bytes (17 x 16B slots)
static constexpr int VROW = 144;    // V_lds row stride bytes (9 x 16B slots)
static constexpr int KTB  = KVB * DD * 2;   // 16384 B packed K tile [64][256B]
static constexpr int VTB  = DD * KVB * 2;   // 16384 B packed V^T tile [128][128B]

typedef __attribute__((ext_vector_type(8)))  short    s16x8;
typedef __attribute__((ext_vector_type(8)))  __bf16   b16x8;
typedef __attribute__((ext_vector_type(16))) float    f32x16;
typedef __attribute__((ext_vector_type(4)))  unsigned u32x4;

// ---- MFMA wrapper: compiles whether the builtin takes short8 or bf16x8 ----
template <typename T>
__device__ __forceinline__ auto mfma_try(T a, T b, f32x16 c, int)
    -> decltype(__builtin_amdgcn_mfma_f32_32x32x16_bf16(a, b, c, 0, 0, 0)) {
  return __builtin_amdgcn_mfma_f32_32x32x16_bf16(a, b, c, 0, 0, 0);
}
template <typename T>
__device__ __forceinline__ f32x16 mfma_try(T a, T b, f32x16 c, long) {
  using O = typename std::conditional<std::is_same<T, s16x8>::value, b16x8, s16x8>::type;
  return __builtin_amdgcn_mfma_f32_32x32x16_bf16(
      __builtin_bit_cast(O, a), __builtin_bit_cast(O, b), c, 0, 0, 0);
}
__device__ __forceinline__ f32x16 mfma32_bf16(s16x8 a, s16x8 b, f32x16 c) {
  return mfma_try(a, b, c, 0);
}

__device__ __forceinline__ short bfb(float x) {
  return (short)__builtin_bit_cast(unsigned short, (__bf16)x);
}
__device__ __forceinline__ unsigned pack_bf16x2(float a, float b) {
  unsigned ua = (unsigned short)__builtin_bit_cast(unsigned short, (__bf16)a);
  unsigned ub = (unsigned short)__builtin_bit_cast(unsigned short, (__bf16)b);
  return ua | (ub << 16);
}
__device__ __forceinline__ f32x16 zero16() {
  f32x16 z;
#pragma unroll
  for (int i = 0; i < 16; ++i) z[i] = 0.0f;
  return z;
}
#define VC(a, i) ((i)==0?(a).x:(i)==1?(a).y:(i)==2?(a).z:(a).w)

// =====================================================================
// Kernel 0: pre-pack K and V to bf16 tiles in d_ws.
//   Kpk: [b][hkv][t][row 0..63][256B]   (row-major bf16, matches LDS copy)
//   Vpk: [b][hkv][t][d 0..127][128B]    (V transposed: row=d, 64 kv bf16)
// =====================================================================
__global__ void __launch_bounds__(256)
pack_kv_kernel(const float* __restrict__ k_in, const float* __restrict__ v_in,
               unsigned char* __restrict__ kpk, unsigned char* __restrict__ vpk)
{
  __shared__ __align__(16) unsigned char Vt[DD * 128];  // [d][64 bf16]

  const int wg  = blockIdx.x;          // (b*HKV+hkv)*NT + t
  const int t   = wg & (NT - 1);
  const int bh  = wg >> 4;             // b*HKV + hkv
  const int tid = threadIdx.x;
  const int row = tid >> 2, c = tid & 3;

  const size_t srow = ((size_t)(bh >> 3) * SS + t * KVB + row) * (HKV * DD)
                    + (size_t)(bh & 7) * DD + c * 32;
  const size_t tile_off = ((size_t)bh * NT + t) * (size_t)KTB;

  // ---- K: straight bf16 pack, row-major ----
  {
    const float* ks = k_in + srow;
    unsigned char* kd = kpk + tile_off + row * 256 + c * 64;
#pragma unroll
    for (int j = 0; j < 4; ++j) {
      const float4 f0 = *(const float4*)(ks + j * 8);
      const float4 f1 = *(const float4*)(ks + j * 8 + 4);
      s16x8 kb;
      kb[0]=bfb(f0.x); kb[1]=bfb(f0.y); kb[2]=bfb(f0.z); kb[3]=bfb(f0.w);
      kb[4]=bfb(f1.x); kb[5]=bfb(f1.y); kb[6]=bfb(f1.z); kb[7]=bfb(f1.w);
      *(s16x8*)(kd + j * 16) = kb;
    }
  }
  // ---- V: transpose via LDS ----
  {
    const float* vs = v_in + srow;
    float4 va[8];
#pragma unroll
    for (int jj = 0; jj < 8; ++jj) va[jj] = *(const float4*)(vs + jj * 4);
#pragma unroll
    for (int jj = 0; jj < 8; ++jj)
#pragma unroll
      for (int e = 0; e < 4; ++e) {
        const int d = c * 32 + jj * 4 + e;
        *(short*)(Vt + d * 128 + row * 2) = bfb(VC(va[jj], e));
      }
  }
  __syncthreads();
  {
    const int d = tid >> 1, hh = tid & 1;
    const unsigned char* src = Vt + d * 128 + hh * 64;
    unsigned char* dst = vpk + tile_off + d * 128 + hh * 64;
#pragma unroll
    for (int j = 0; j < 4; ++j)
      *(float4*)(dst + j * 16) = *(const float4*)(src + j * 16);
  }
}

// =====================================================================
// Kernel 1: paged KV-cache update (exact fp32 copy).
// =====================================================================
__global__ void __launch_bounds__(256)
cache_scatter_kernel(const float* __restrict__ k_in, const float* __restrict__ v_in,
                     const float* __restrict__ kc_in, const float* __restrict__ vc_in,
                     const int* __restrict__ bidx, int n_used,
                     float* __restrict__ kc_out, float* __restrict__ vc_out)
{
  const int BLK_ELEMS = PAGE * HKV * DD;
  const int wg    = blockIdx.x;
  const int chunk = wg & 7;
  const int which = (wg >> 3) & 1;
  const int cb    = wg >> 4;

  int src_blk = -1;
  for (int i = 0; i < n_used; ++i)
    if (bidx[i] == cb) src_blk = i;        // last match wins

  const float* src;
  float* dst;
  if (which == 0) {
    src = (src_blk >= 0) ? (k_in + (size_t)src_blk * BLK_ELEMS)
                         : (kc_in + (size_t)cb * BLK_ELEMS);
    dst = kc_out + (size_t)cb * BLK_ELEMS;
  } else {
    src = (src_blk >= 0) ? (v_in + (size_t)src_blk * BLK_ELEMS)
                         : (vc_in + (size_t)cb * BLK_ELEMS);
    dst = vc_out + (size_t)cb * BLK_ELEMS;
  }
  const int CHUNK = BLK_ELEMS / 8;
  const float4* s4 = (const float4*)(src + chunk * CHUNK);
  float4*       d4 = (float4*)(dst + chunk * CHUNK);
#pragma unroll 4
  for (int i = threadIdx.x; i < CHUNK / 4; i += 256) d4[i] = s4[i];
}

// =====================================================================
// Kernel 2: causal + ALiBi GQA prefill attention, bf16 MFMA 32x32x16.
// Per-wg balanced pair of q-tiles; double-buffered LDS; one barrier per
// kv tile; staging is a pure bf16 byte copy (8 loads + 8 b128 writes).
// =====================================================================

#define STAGE_LOAD(T) do {                                               \
    const unsigned char* ks_ = kpk_t + (size_t)(T) * KTB;                \
    pk0 = *(const float4*)(ks_ +  0); pk1 = *(const float4*)(ks_ + 16);  \
    pk2 = *(const float4*)(ks_ + 32); pk3 = *(const float4*)(ks_ + 48);  \
    const unsigned char* vs_ = vpk_t + (size_t)(T) * VTB;                \
    pv0 = *(const float4*)(vs_ +  0); pv1 = *(const float4*)(vs_ + 16);  \
    pv2 = *(const float4*)(vs_ + 32); pv3 = *(const float4*)(vs_ + 48);  \
    asm volatile("" :: "v"(pk0.x), "v"(pk1.x), "v"(pk2.x), "v"(pk3.x),   \
                       "v"(pv0.x), "v"(pv1.x), "v"(pv2.x), "v"(pv3.x));  \
  } while(0)

#define STAGE_WRITE(B) do {                                              \
    unsigned char* dk_ = dk0 + (B) * (KVB * KROW);                       \
    *(float4*)(dk_ +  0) = pk0; *(float4*)(dk_ + 16) = pk1;              \
    *(float4*)(dk_ + 32) = pk2; *(float4*)(dk_ + 48) = pk3;              \
    unsigned char* dv_ = dv0 + (B) * (DD * VROW);                        \
    *(float4*)(dv_ +  0) = pv0; *(float4*)(dv_ + 16) = pv1;              \
    *(float4*)(dv_ + 32) = pv2; *(float4*)(dv_ + 48) = pv3;              \
  } while(0)

__global__ void __launch_bounds__(256, 2)
attn_kernel(const float* __restrict__ q_in,
            const unsigned char* __restrict__ kpk,
            const unsigned char* __restrict__ vpk,
            const float* __restrict__ slopes, float* __restrict__ out)
{
  __shared__ __align__(16) unsigned char K_lds[2][KVB * KROW];  // 2x17408
  __shared__ __align__(16) unsigned char V_lds[2][DD * VROW];   // 2x18432

  const int wgid0 = blockIdx.x;
  const int wgid  = ((wgid0 & 7) << 6) | (wgid0 >> 3);  // XCD-chunked swizzle
  const int qtp = wgid & 3;
  const int g   = (wgid >> 2) & 3;
  const int hkv = (wgid >> 4) & 7;
  const int b   = wgid >> 7;
  const int h   = hkv * GG + g;

  const int tid  = threadIdx.x;
  const int w    = tid >> 6;
  const int lane = tid & 63;
  const int ln   = lane & 31;
  const int hi   = lane >> 5;

  const float LOG2E  = 1.44269504088896340736f;
  const float QSCALE = 0.08838834764831845f * LOG2E;
  const float slope2 = slopes[h] * LOG2E;

  const size_t tile_base = (size_t)(b * HKV + hkv) * NT * (size_t)KTB;
  const unsigned char* kpk_t = kpk + tile_base + (size_t)tid * 64;
  const unsigned char* vpk_t = vpk + tile_base + (size_t)tid * 64;
  unsigned char* dk0 = &K_lds[0][(tid >> 2) * KROW + (tid & 3) * 64];
  unsigned char* dv0 = &V_lds[0][(tid >> 1) * VROW + (tid & 1) * 64];

  const size_t bs_off = (size_t)b * SS;
  int bufc = 0;

  float4 pk0, pk1, pk2, pk3, pv0, pv1, pv2, pv3;

  for (int pass = 0; pass < 2; ++pass) {
    const int qt    = pass ? qtp : (7 - qtp);
    const int qb    = qt * QBLK;
    const int qg    = qb + w * 32 + ln;
    const int qwmax = qb + w * 32 + 31;
    const int nt    = 2 * qt + 2;

    // ---- Q fragments, pre-scaled ----
    s16x8 qfrag[8];
    {
      const float* qrow = q_in + ((bs_off + qg) * HH + h) * DD;
#pragma unroll
      for (int ks = 0; ks < 8; ++ks) {
        const float4 f0 = *(const float4*)(qrow + ks * 16 + hi * 8);
        const float4 f1 = *(const float4*)(qrow + ks * 16 + hi * 8 + 4);
        s16x8 qv;
        qv[0] = bfb(f0.x * QSCALE); qv[1] = bfb(f0.y * QSCALE);
        qv[2] = bfb(f0.z * QSCALE); qv[3] = bfb(f0.w * QSCALE);
        qv[4] = bfb(f1.x * QSCALE); qv[5] = bfb(f1.y * QSCALE);
        qv[6] = bfb(f1.z * QSCALE); qv[7] = bfb(f1.w * QSCALE);
        qfrag[ks] = qv;
      }
    }

    f32x16 acc[4];
#pragma unroll
    for (int m = 0; m < 4; ++m) acc[m] = zero16();
    float mrun = -INFINITY, lrun = 0.0f;

    // ---- prologue: stage tile 0 into bufc ----
    STAGE_LOAD(0);
    STAGE_WRITE(bufc);
    __syncthreads();

    for (int t = 0; t < nt; ++t) {
      const int kvb = t * KVB;
      const bool pf = (t + 1 < nt);
      if (pf) STAGE_LOAD(t + 1);         // issue early (hidden under compute)

      if (kvb <= qwmax) {
        const unsigned char* kb = &K_lds[bufc][0];
        const unsigned char* vb = &V_lds[bufc][0];

        // ---- S^T = K * Q^T ----
        f32x16 sc[2];
        __builtin_amdgcn_s_setprio(1);
#pragma unroll
        for (int kt = 0; kt < 2; ++kt) {
          f32x16 a = zero16();
          const unsigned char* krow = kb + (kt * 32 + ln) * KROW + hi * 16;
#pragma unroll
          for (int ks = 0; ks < 8; ++ks) {
            const s16x8 af = *(const s16x8*)(krow + ks * 32);
            a = mfma32_bf16(af, qfrag[ks], a);
          }
          sc[kt] = a;
        }
        __builtin_amdgcn_s_setprio(0);

        // ---- ALiBi + causal + online softmax (log2 domain) ----
        float pm = -INFINITY;
#pragma unroll
        for (int kt = 0; kt < 2; ++kt)
#pragma unroll
          for (int r = 0; r < 16; ++r) {
            const int kvg = kvb + kt * 32 + (r & 3) + 8 * (r >> 2) + 4 * hi;
            float lg = sc[kt][r] + slope2 * (float)(kvg - qg);
            lg = (kvg <= qg) ? lg : -INFINITY;
            sc[kt][r] = lg;
            pm = fmaxf(pm, lg);
          }
        pm = fmaxf(pm, __shfl_xor(pm, 32));
        const float mnew = fmaxf(mrun, pm);
        const float fac  = __builtin_exp2f(mrun - mnew);
        float rs = 0.0f;
        unsigned Wp[2][4][2];
#pragma unroll
        for (int kt = 0; kt < 2; ++kt) {
#pragma unroll
          for (int r = 0; r < 16; ++r) {
            const float pv = __builtin_exp2f(sc[kt][r] - mnew);
            sc[kt][r] = pv;
            rs += pv;
          }
#pragma unroll
          for (int m = 0; m < 4; ++m)
#pragma unroll
            for (int s = 0; s < 2; ++s)
              Wp[kt][m][s] = pack_bf16x2(sc[kt][4 * m + 2 * s], sc[kt][4 * m + 2 * s + 1]);
        }
        rs += __shfl_xor(rs, 32);
        lrun = lrun * fac + rs;
        mrun = mnew;
#pragma unroll
        for (int m = 0; m < 4; ++m)
#pragma unroll
          for (int r = 0; r < 16; ++r) acc[m][r] *= fac;

        // ---- O^T += V^T * P^T, P fragments built in-register ----
        __builtin_amdgcn_s_setprio(1);
#pragma unroll
        for (int ksv = 0; ksv < 4; ++ksv) {
          const int kt = ksv >> 1, k2 = ksv & 1;
          const unsigned a0 = hi ? Wp[kt][2 * k2][0] : Wp[kt][2 * k2 + 1][0];
          const unsigned a1 = hi ? Wp[kt][2 * k2][1] : Wp[kt][2 * k2 + 1][1];
          const unsigned x0 = __shfl_xor(a0, 32);
          const unsigned x1 = __shfl_xor(a1, 32);
          const unsigned f0 = hi ? x0 : Wp[kt][2 * k2][0];
          const unsigned f1 = hi ? x1 : Wp[kt][2 * k2][1];
          const unsigned f2 = hi ? Wp[kt][2 * k2 + 1][0] : x0;
          const unsigned f3 = hi ? Wp[kt][2 * k2 + 1][1] : x1;
          const u32x4 fw = {f0, f1, f2, f3};
          const s16x8 pfrag = __builtin_bit_cast(s16x8, fw);
#pragma unroll
          for (int m = 0; m < 4; ++m) {
            const s16x8 vf = *(const s16x8*)(vb + (m * 32 + ln) * VROW + ksv * 32 + hi * 16);
            acc[m] = mfma32_bf16(vf, pfrag, acc[m]);
          }
        }
        __builtin_amdgcn_s_setprio(0);
      }

      if (pf) STAGE_WRITE(bufc ^ 1);     // vmcnt waits here; writes other buffer
      __syncthreads();                   // one barrier per tile
      bufc ^= 1;
    }

    // ---- epilogue: O = O^T / l ----
    const float rinv = 1.0f / lrun;
    float* orow = out + ((bs_off + qg) * HH + h) * DD;
#pragma unroll
    for (int m = 0; m < 4; ++m)
#pragma unroll
      for (int rq = 0; rq < 4; ++rq) {
        float4 o;
        o.x = acc[m][4 * rq + 0] * rinv;
        o.y = acc[m][4 * rq + 1] * rinv;
        o.z = acc[m][4 * rq + 2] * rinv;
        o.w = acc[m][4 * rq + 3] * rinv;
        *(float4*)(orow + m * 32 + 8 * rq + 4 * hi) = o;
      }
  }
}

// =====================================================================
extern "C" void kernel_launch(void* const* d_in, const int* in_sizes, int n_in,
                              void* d_out, int out_size, void* d_ws, size_t ws_size,
                              hipStream_t stream)
{
  const float* query  = (const float*)d_in[0];
  const float* key    = (const float*)d_in[1];
  const float* value  = (const float*)d_in[2];
  const float* kc_in  = (const float*)d_in[3];
  const float* vc_in  = (const float*)d_in[4];
  const int*   bidx   = (const int*)d_in[5];
  const float* slopes = (const float*)d_in[6];
  const int n_used = in_sizes[5];

  float* out_attn = (float*)d_out;
  float* kc_out   = out_attn + (size_t)BB * SS * HH * DD;
  float* vc_out   = kc_out + (size_t)NBLK * PAGE * HKV * DD;

  unsigned char* kpk = (unsigned char*)d_ws;                       // 8.4 MB
  unsigned char* vpk = kpk + (size_t)BB * HKV * SS * DD * 2;       // 8.4 MB

  hipLaunchKernelGGL(pack_kv_kernel, dim3(BB * HKV * NT), dim3(256), 0, stream,
                     key, value, kpk, vpk);
  hipLaunchKernelGGL(attn_kernel, dim3(BB * HKV * GG * 4), dim3(256), 0, stream,
                     query, kpk, vpk, slopes, out_attn);
  hipLaunchKernelGGL(cache_scatter_kernel, dim3(NBLK * 2 * 8), dim3(256), 0, stream,
                     key, value, kc_in, vc_in, bidx, n_used, kc_out, vc_out);
}

// Round 4
// 125.300 us; speedup vs baseline: 1.3020x; 1.3020x over previous
//
#include <hip/hip_runtime.h>
#include <hip/hip_bf16.h>
#include <type_traits>
#include <stdint.h>

// ---- problem constants ----
static constexpr int BB   = 4;
static constexpr int SS   = 1024;
static constexpr int HH   = 32;
static constexpr int HKV  = 8;
static constexpr int GG   = 4;      // H / HKV
static constexpr int DD   = 128;
static constexpr int PAGE = 128;    // paged-cache block size
static constexpr int NBLK = 64;     // cache blocks
static constexpr int QBLK = 128;    // q rows per q-tile (4 waves x 32)
static constexpr int KVB  = 64;     // kv rows per tile
static constexpr int NT   = SS / KVB;   // 16 kv tiles per (b,hkv)
static constexpr int KTB  = 16384;  // packed tile bytes (K and V alike: [64][256B])

typedef __attribute__((ext_vector_type(8)))  short    s16x8;
typedef __attribute__((ext_vector_type(8)))  __bf16   b16x8;
typedef __attribute__((ext_vector_type(16))) float    f32x16;
typedef __attribute__((ext_vector_type(4)))  unsigned u32x4;

// ---- MFMA wrapper: compiles whether the builtin takes short8 or bf16x8 ----
template <typename T>
__device__ __forceinline__ auto mfma_try(T a, T b, f32x16 c, int)
    -> decltype(__builtin_amdgcn_mfma_f32_32x32x16_bf16(a, b, c, 0, 0, 0)) {
  return __builtin_amdgcn_mfma_f32_32x32x16_bf16(a, b, c, 0, 0, 0);
}
template <typename T>
__device__ __forceinline__ f32x16 mfma_try(T a, T b, f32x16 c, long) {
  using O = typename std::conditional<std::is_same<T, s16x8>::value, b16x8, s16x8>::type;
  return __builtin_amdgcn_mfma_f32_32x32x16_bf16(
      __builtin_bit_cast(O, a), __builtin_bit_cast(O, b), c, 0, 0, 0);
}
__device__ __forceinline__ f32x16 mfma32_bf16(s16x8 a, s16x8 b, f32x16 c) {
  return mfma_try(a, b, c, 0);
}

__device__ __forceinline__ short bfb(float x) {
  return (short)__builtin_bit_cast(unsigned short, (__bf16)x);
}
__device__ __forceinline__ unsigned pack_bf16x2(float a, float b) {
  unsigned ua = (unsigned short)__builtin_bit_cast(unsigned short, (__bf16)a);
  unsigned ub = (unsigned short)__builtin_bit_cast(unsigned short, (__bf16)b);
  return ua | (ub << 16);
}
__device__ __forceinline__ f32x16 zero16() {
  f32x16 z;
#pragma unroll
  for (int i = 0; i < 16; ++i) z[i] = 0.0f;
  return z;
}
__device__ __forceinline__ void gload16(const unsigned char* g, unsigned char* l) {
  __builtin_amdgcn_global_load_lds(
      (const __attribute__((address_space(1))) unsigned*)g,
      (__attribute__((address_space(3))) unsigned*)(unsigned*)l, 16, 0, 0);
}
#define VC(a, i) ((i)==0?(a).x:(i)==1?(a).y:(i)==2?(a).z:(a).w)

// =====================================================================
// Kernel 0: pre-pack K and V to SWIZZLED bf16 tiles in d_ws.
//   Both tiles are [row 0..63][256B], 16 chunks of 16B per row, stored at
//   chunk position (src_chunk ^ (row & 15))  -> LDS image == global image
//   (global_load_lds is linear), ds_read applies the same XOR.
//   K tile row r = kv row r, chunks = d/8.
//   V tile row r = d-rows r (bytes 0..127) and r+64 (bytes 128..255), kv cols.
// =====================================================================
__global__ void __launch_bounds__(256)
pack_kv_kernel(const float* __restrict__ k_in, const float* __restrict__ v_in,
               unsigned char* __restrict__ kpk, unsigned char* __restrict__ vpk)
{
  __shared__ __align__(16) unsigned char Vt[DD * 136];  // [d][64 bf16], padded

  const int wg  = blockIdx.x;          // (b*HKV+hkv)*NT + t
  const int t   = wg & (NT - 1);
  const int bh  = wg >> 4;             // b*HKV + hkv
  const int tid = threadIdx.x;
  const int row = tid >> 2, c = tid & 3;

  const size_t srow = ((size_t)(bh >> 3) * SS + t * KVB + row) * (HKV * DD)
                    + (size_t)(bh & 7) * DD + c * 32;
  const size_t tile_off = ((size_t)bh * NT + t) * (size_t)KTB;

  // ---- K: bf16 pack, swizzled chunk placement ----
  {
    const float* ks = k_in + srow;
    unsigned char* kd = kpk + tile_off + row * 256;
#pragma unroll
    for (int j = 0; j < 4; ++j) {
      const float4 f0 = *(const float4*)(ks + j * 8);
      const float4 f1 = *(const float4*)(ks + j * 8 + 4);
      s16x8 kb;
      kb[0]=bfb(f0.x); kb[1]=bfb(f0.y); kb[2]=bfb(f0.z); kb[3]=bfb(f0.w);
      kb[4]=bfb(f1.x); kb[5]=bfb(f1.y); kb[6]=bfb(f1.z); kb[7]=bfb(f1.w);
      *(s16x8*)(kd + (((c * 4 + j) ^ (row & 15)) << 4)) = kb;
    }
  }
  // ---- V: transpose via LDS ----
  {
    const float* vs = v_in + srow;
    float4 va[8];
#pragma unroll
    for (int jj = 0; jj < 8; ++jj) va[jj] = *(const float4*)(vs + jj * 4);
#pragma unroll
    for (int jj = 0; jj < 8; ++jj)
#pragma unroll
      for (int e = 0; e < 4; ++e) {
        const int d = c * 32 + jj * 4 + e;
        *(short*)(Vt + d * 136 + row * 2) = bfb(VC(va[jj], e));
      }
  }
  __syncthreads();
  {
    const int r = tid >> 2, q = tid & 3;
    unsigned char* vd = vpk + tile_off + r * 256;
#pragma unroll
    for (int jj = 0; jj < 4; ++jj) {
      const int cj  = q * 4 + jj;
      const int d   = r + ((cj >> 3) ? 64 : 0);
      const float4 chunk = *(const float4*)(Vt + d * 136 + (cj & 7) * 16);
      *(float4*)(vd + ((cj ^ (r & 15)) << 4)) = chunk;
    }
  }
}

// =====================================================================
// Kernel 1: paged KV-cache update (exact fp32 copy).
// =====================================================================
__global__ void __launch_bounds__(256)
cache_scatter_kernel(const float* __restrict__ k_in, const float* __restrict__ v_in,
                     const float* __restrict__ kc_in, const float* __restrict__ vc_in,
                     const int* __restrict__ bidx, int n_used,
                     float* __restrict__ kc_out, float* __restrict__ vc_out)
{
  const int BLK_ELEMS = PAGE * HKV * DD;
  const int wg    = blockIdx.x;
  const int chunk = wg & 7;
  const int which = (wg >> 3) & 1;
  const int cb    = wg >> 4;

  int src_blk = -1;
  for (int i = 0; i < n_used; ++i)
    if (bidx[i] == cb) src_blk = i;        // last match wins

  const float* src;
  float* dst;
  if (which == 0) {
    src = (src_blk >= 0) ? (k_in + (size_t)src_blk * BLK_ELEMS)
                         : (kc_in + (size_t)cb * BLK_ELEMS);
    dst = kc_out + (size_t)cb * BLK_ELEMS;
  } else {
    src = (src_blk >= 0) ? (v_in + (size_t)src_blk * BLK_ELEMS)
                         : (vc_in + (size_t)cb * BLK_ELEMS);
    dst = vc_out + (size_t)cb * BLK_ELEMS;
  }
  const int CHUNK = BLK_ELEMS / 8;
  const float4* s4 = (const float4*)(src + chunk * CHUNK);
  float4*       d4 = (float4*)(dst + chunk * CHUNK);
#pragma unroll 4
  for (int i = threadIdx.x; i < CHUNK / 4; i += 256) d4[i] = s4[i];
}

// =====================================================================
// Kernel 2: causal + ALiBi GQA prefill attention, bf16 MFMA 32x32x16.
// Staging via global_load_lds (zero VGPR cost); double-buffered LDS;
// one barrier per kv tile (drains vmcnt); pre-swizzled tiles -> 2-way
// bank conflicts on all ds_read_b128.
// =====================================================================

// wave w stages bytes [w*4096, w*4096+4096) of each 16 KB tile
#define STAGE(T, B) do {                                                     \
    const unsigned char* ks_ = kpk_w + (size_t)(T) * KTB;                    \
    const unsigned char* vs_ = vpk_w + (size_t)(T) * KTB;                    \
    unsigned char* kl_ = &K_lds[B][w * 4096 + (size_t)lane * 16];            \
    unsigned char* vl_ = &V_lds[B][w * 4096 + (size_t)lane * 16];            \
    gload16(ks_ +    0, kl_ +    0); gload16(ks_ + 1024, kl_ + 1024);        \
    gload16(ks_ + 2048, kl_ + 2048); gload16(ks_ + 3072, kl_ + 3072);       \
    gload16(vs_ +    0, vl_ +    0); gload16(vs_ + 1024, vl_ + 1024);        \
    gload16(vs_ + 2048, vl_ + 2048); gload16(vs_ + 3072, vl_ + 3072);       \
  } while(0)

__global__ void __launch_bounds__(256, 2)
attn_kernel(const float* __restrict__ q_in,
            const unsigned char* __restrict__ kpk,
            const unsigned char* __restrict__ vpk,
            const float* __restrict__ slopes, float* __restrict__ out)
{
  __shared__ __align__(16) unsigned char K_lds[2][KVB * 256];  // 2 x 16 KB
  __shared__ __align__(16) unsigned char V_lds[2][KVB * 256];  // 2 x 16 KB

  const int wgid0 = blockIdx.x;
  const int wgid  = ((wgid0 & 7) << 6) | (wgid0 >> 3);  // XCD-chunked swizzle
  const int qtp = wgid & 3;
  const int g   = (wgid >> 2) & 3;
  const int hkv = (wgid >> 4) & 7;
  const int b   = wgid >> 7;
  const int h   = hkv * GG + g;

  const int tid  = threadIdx.x;
  const int w    = tid >> 6;
  const int lane = tid & 63;
  const int ln   = lane & 31;
  const int hi   = lane >> 5;

  const float LOG2E  = 1.44269504088896340736f;
  const float QSCALE = 0.08838834764831845f * LOG2E;
  const float slope2 = slopes[h] * LOG2E;

  const size_t tile_base = (size_t)(b * HKV + hkv) * NT * (size_t)KTB;
  const unsigned char* kpk_w = kpk + tile_base + w * 4096 + (size_t)lane * 16;
  const unsigned char* vpk_w = vpk + tile_base + w * 4096 + (size_t)lane * 16;

  // per-lane ds_read addressing pieces
  const int lnbase = ln * 256;          // LDS row base
  const int lnsw   = (ln & 15) << 4;    // swizzle XOR for this lane's rows
  const int hib    = hi * 16;

  const size_t bs_off = (size_t)b * SS;
  int bufc = 0;

  for (int pass = 0; pass < 2; ++pass) {
    const int qt    = pass ? qtp : (7 - qtp);
    const int qb    = qt * QBLK;
    const int qg    = qb + w * 32 + ln;
    const int qwmax = qb + w * 32 + 31;
    const int nt    = 2 * qt + 2;

    // ---- Q fragments, pre-scaled ----
    s16x8 qfrag[8];
    {
      const float* qrow = q_in + ((bs_off + qg) * HH + h) * DD;
#pragma unroll
      for (int ks = 0; ks < 8; ++ks) {
        const float4 f0 = *(const float4*)(qrow + ks * 16 + hi * 8);
        const float4 f1 = *(const float4*)(qrow + ks * 16 + hi * 8 + 4);
        s16x8 qv;
        qv[0] = bfb(f0.x * QSCALE); qv[1] = bfb(f0.y * QSCALE);
        qv[2] = bfb(f0.z * QSCALE); qv[3] = bfb(f0.w * QSCALE);
        qv[4] = bfb(f1.x * QSCALE); qv[5] = bfb(f1.y * QSCALE);
        qv[6] = bfb(f1.z * QSCALE); qv[7] = bfb(f1.w * QSCALE);
        qfrag[ks] = qv;
      }
    }

    f32x16 acc[4];
#pragma unroll
    for (int m = 0; m < 4; ++m) acc[m] = zero16();
    float mrun = -INFINITY, lrun = 0.0f;

    // ---- prologue: stage tile 0 ----
    STAGE(0, bufc);
    __syncthreads();

    for (int t = 0; t < nt; ++t) {
      const int kvb = t * KVB;
      if (t + 1 < nt) STAGE(t + 1, bufc ^ 1);   // in flight under compute

      if (kvb <= qwmax) {
        const unsigned char* kb = &K_lds[bufc][0];
        const unsigned char* vb = &V_lds[bufc][0];

        // ---- S^T = K * Q^T ----
        f32x16 sc[2];
        __builtin_amdgcn_s_setprio(1);
#pragma unroll
        for (int kt = 0; kt < 2; ++kt) {
          f32x16 a = zero16();
          const unsigned char* krow = kb + kt * 8192 + lnbase;
#pragma unroll
          for (int ks = 0; ks < 8; ++ks) {
            const s16x8 af = *(const s16x8*)(krow + ((ks * 32 + hib) ^ lnsw));
            a = mfma32_bf16(af, qfrag[ks], a);
          }
          sc[kt] = a;
        }
        __builtin_amdgcn_s_setprio(0);

        // ---- ALiBi + causal + online softmax (log2 domain) ----
        float pm = -INFINITY;
#pragma unroll
        for (int kt = 0; kt < 2; ++kt)
#pragma unroll
          for (int r = 0; r < 16; ++r) {
            const int kvg = kvb + kt * 32 + (r & 3) + 8 * (r >> 2) + 4 * hi;
            float lg = sc[kt][r] + slope2 * (float)(kvg - qg);
            lg = (kvg <= qg) ? lg : -INFINITY;
            sc[kt][r] = lg;
            pm = fmaxf(pm, lg);
          }
        pm = fmaxf(pm, __shfl_xor(pm, 32));
        const float mnew = fmaxf(mrun, pm);
        const float fac  = __builtin_exp2f(mrun - mnew);
        float rs = 0.0f;
        unsigned Wp[2][4][2];
#pragma unroll
        for (int kt = 0; kt < 2; ++kt) {
#pragma unroll
          for (int r = 0; r < 16; ++r) {
            const float pv = __builtin_exp2f(sc[kt][r] - mnew);
            sc[kt][r] = pv;
            rs += pv;
          }
#pragma unroll
          for (int m = 0; m < 4; ++m)
#pragma unroll
            for (int s = 0; s < 2; ++s)
              Wp[kt][m][s] = pack_bf16x2(sc[kt][4 * m + 2 * s], sc[kt][4 * m + 2 * s + 1]);
        }
        rs += __shfl_xor(rs, 32);
        lrun = lrun * fac + rs;
        mrun = mnew;
#pragma unroll
        for (int m = 0; m < 4; ++m)
#pragma unroll
          for (int r = 0; r < 16; ++r) acc[m][r] *= fac;

        // ---- O^T += V^T * P^T, P fragments built in-register ----
        __builtin_amdgcn_s_setprio(1);
#pragma unroll
        for (int ksv = 0; ksv < 4; ++ksv) {
          const int kt = ksv >> 1, k2 = ksv & 1;
          const unsigned a0 = hi ? Wp[kt][2 * k2][0] : Wp[kt][2 * k2 + 1][0];
          const unsigned a1 = hi ? Wp[kt][2 * k2][1] : Wp[kt][2 * k2 + 1][1];
          const unsigned x0 = __shfl_xor(a0, 32);
          const unsigned x1 = __shfl_xor(a1, 32);
          const unsigned f0 = hi ? x0 : Wp[kt][2 * k2][0];
          const unsigned f1 = hi ? x1 : Wp[kt][2 * k2][1];
          const unsigned f2 = hi ? Wp[kt][2 * k2 + 1][0] : x0;
          const unsigned f3 = hi ? Wp[kt][2 * k2 + 1][1] : x1;
          const u32x4 fw = {f0, f1, f2, f3};
          const s16x8 pfrag = __builtin_bit_cast(s16x8, fw);
#pragma unroll
          for (int m = 0; m < 4; ++m) {
            // V^T row d = m*32+ln lives at LDS row (m&1)*32+ln, half (m>>1)
            const s16x8 vf = *(const s16x8*)(vb + (m & 1) * 8192 + lnbase +
                                             (((m >> 1) * 128 + ksv * 32 + hib) ^ lnsw));
            acc[m] = mfma32_bf16(vf, pfrag, acc[m]);
          }
        }
        __builtin_amdgcn_s_setprio(0);
      }

      __syncthreads();                 // drains vmcnt: tile t+1 staged & visible
      bufc ^= 1;
    }

    // ---- epilogue: O = O^T / l ----
    const float rinv = 1.0f / lrun;
    float* orow = out + ((bs_off + qg) * HH + h) * DD;
#pragma unroll
    for (int m = 0; m < 4; ++m)
#pragma unroll
      for (int rq = 0; rq < 4; ++rq) {
        float4 o;
        o.x = acc[m][4 * rq + 0] * rinv;
        o.y = acc[m][4 * rq + 1] * rinv;
        o.z = acc[m][4 * rq + 2] * rinv;
        o.w = acc[m][4 * rq + 3] * rinv;
        *(float4*)(orow + m * 32 + 8 * rq + 4 * hi) = o;
      }
  }
}

// =====================================================================
extern "C" void kernel_launch(void* const* d_in, const int* in_sizes, int n_in,
                              void* d_out, int out_size, void* d_ws, size_t ws_size,
                              hipStream_t stream)
{
  const float* query  = (const float*)d_in[0];
  const float* key    = (const float*)d_in[1];
  const float* value  = (const float*)d_in[2];
  const float* kc_in  = (const float*)d_in[3];
  const float* vc_in  = (const float*)d_in[4];
  const int*   bidx   = (const int*)d_in[5];
  const float* slopes = (const float*)d_in[6];
  const int n_used = in_sizes[5];

  float* out_attn = (float*)d_out;
  float* kc_out   = out_attn + (size_t)BB * SS * HH * DD;
  float* vc_out   = kc_out + (size_t)NBLK * PAGE * HKV * DD;

  unsigned char* kpk = (unsigned char*)d_ws;                       // 16.8 MB
  unsigned char* vpk = kpk + (size_t)BB * HKV * SS * DD * 2;       // 16.8 MB

  hipLaunchKernelGGL(pack_kv_kernel, dim3(BB * HKV * NT), dim3(256), 0, stream,
                     key, value, kpk, vpk);
  hipLaunchKernelGGL(attn_kernel, dim3(BB * HKV * GG * 4), dim3(256), 0, stream,
                     query, kpk, vpk, slopes, out_attn);
  hipLaunchKernelGGL(cache_scatter_kernel, dim3(NBLK * 2 * 8), dim3(256), 0, stream,
                     key, value, kc_in, vc_in, bidx, n_used, kc_out, vc_out);
}